// Round 4
// baseline (335.195 us; speedup 1.0000x reference)
//
#include <hip/hip_runtime.h>
#include <hip/hip_bf16.h>
#include <math.h>

// Problem constants (B=4, T=2048, C=1024, H=16, D=64)
#define SEQ   2048
#define NTOK  8192          // B*T
#define EMB   1024
#define QKVF  3072

typedef __bf16 bf16;
typedef __bf16 bf16x8 __attribute__((ext_vector_type(8)));
typedef __bf16 bf16x4 __attribute__((ext_vector_type(4)));
typedef float  f32x4  __attribute__((ext_vector_type(4)));

__device__ __forceinline__ void gload_lds16(const bf16* g, bf16* l) {
    __builtin_amdgcn_global_load_lds(
        (const __attribute__((address_space(1))) unsigned int*)g,
        (__attribute__((address_space(3))) unsigned int*)l,
        16, 0, 0);
}

// ---------------- fp32 -> bf16 conversion (vectorized x4) ----------------
__global__ __launch_bounds__(256) void cvt_f32_bf16(const float* __restrict__ in,
                                                    bf16* __restrict__ out, int n) {
    int i = (blockIdx.x * 256 + threadIdx.x) * 4;
    if (i >= n) return;
    float4 f = *reinterpret_cast<const float4*>(in + i);
    bf16x4 o;
    o[0] = (bf16)f.x; o[1] = (bf16)f.y; o[2] = (bf16)f.z; o[3] = (bf16)f.w;
    *reinterpret_cast<bf16x4*>(out + i) = o;
}

// ---------------- 8-wave pipelined bt-GEMM: C[M,N] = A[M,K]*B[N,K]^T + bias ----
// BM=256, BN=NF*64, BK=64. 512 threads = 8 waves (2x4). Per-wave out 128x(NF*16).
// Double-buffered swizzled LDS, 4 phases/K-tile, counted vmcnt, setprio.
// B swizzle key = (row>>1)&3 so each ds_read_b128 tiles a contiguous 1KB region
// (conflict-free); old (row&3) key was a 4-way conflict.
template <int NF, bool BF16OUT>
__global__ __launch_bounds__(512, 2) void gemm_bt8(const bf16* __restrict__ A,
                                                   const bf16* __restrict__ Bm,
                                                   const float* __restrict__ bias,
                                                   void* __restrict__ out,
                                                   int M, int N, int K) {
    constexpr int NBR = NF / 2;          // B staging rounds per K-panel
    constexpr int WN  = NBR + 2;         // counted-vmcnt immediate
    __shared__ bf16 As[2][256 * 64];             // [buf][row*64 + chunk*8], swizzled
    __shared__ bf16 Bs[2][2][NF * 64 * 32];      // [buf][kk][row*32 + chunk*8], swizzled

    const int nbx = N / (NF * 64);
    const int nwg = nbx * (M >> 8);
    const int q8  = nwg >> 3;
    const int swz = ((int)blockIdx.x & 7) * q8 + ((int)blockIdx.x >> 3);
    const int bx  = swz % nbx;
    const int by  = swz / nbx;

    const int tid  = threadIdx.x;
    const int lane = tid & 63;
    const int wid  = tid >> 6;
    const int wr   = wid >> 2, wc = wid & 3;
    const int lr   = lane & 15, hi = lane >> 4;
    const size_t brow = (size_t)by * 256;
    const size_t bcol = (size_t)bx * (NF * 64);

    const f32x4 fzero = {0.f, 0.f, 0.f, 0.f};
    f32x4 acc[8][NF];
#pragma unroll
    for (int m = 0; m < 8; ++m)
#pragma unroll
        for (int n = 0; n < NF; ++n) acc[m][n] = fzero;

#define STAGE_A_ROUND(b, kt, r) do {                                            \
    const int row_ = (r) * 64 + (tid >> 3);                                     \
    const int cg_  = (tid & 7) ^ (row_ & 7);                                    \
    gload_lds16(A + (brow + row_) * (size_t)K + (size_t)(kt) * 64 + cg_ * 8,    \
                &As[b][(r) * 4096 + tid * 8]);                                  \
} while (0)
#define STAGE_B_ROUND(b, kt, kkp, rr) do {                                      \
    const int row_ = (rr) * 128 + (tid >> 2);                                   \
    const int cg_  = (tid & 3) ^ ((row_ >> 1) & 3);                             \
    gload_lds16(Bm + (bcol + row_) * (size_t)K + (size_t)(kt) * 64 +            \
                    (kkp) * 32 + cg_ * 8,                                       \
                &Bs[b][kkp][(rr) * 4096 + tid * 8]);                            \
} while (0)
#define ISSUE_G1(b, kt) do { STAGE_A_ROUND(b, kt, 0); STAGE_A_ROUND(b, kt, 2);  \
    for (int rr_ = 0; rr_ < NBR; ++rr_) STAGE_B_ROUND(b, kt, 0, rr_); } while (0)
#define ISSUE_G2(b, kt) do {                                                    \
    for (int rr_ = 0; rr_ < NBR; ++rr_) STAGE_B_ROUND(b, kt, 1, rr_); } while (0)
#define ISSUE_G3(b, kt) do { STAGE_A_ROUND(b, kt, 1); STAGE_A_ROUND(b, kt, 3); } while (0)

#define READ_A(b, mh, kk, dst) do {                                             \
    _Pragma("unroll")                                                           \
    for (int i_ = 0; i_ < 4; ++i_) {                                            \
        const int row_ = wr * 128 + (mh) * 64 + i_ * 16 + lr;                   \
        dst[i_] = *reinterpret_cast<const bf16x8*>(                             \
            (const char*)&As[b][0] + row_ * 128 +                               \
            (((kk) * 64 + hi * 16) ^ ((row_ & 7) << 4)));                       \
    }                                                                           \
} while (0)
#define READ_B(b, kk, dst) do {                                                 \
    _Pragma("unroll")                                                           \
    for (int n_ = 0; n_ < NF; ++n_) {                                           \
        const int row_ = wc * (NF * 16) + n_ * 16 + lr;                         \
        dst[n_] = *reinterpret_cast<const bf16x8*>(                             \
            (const char*)&Bs[b][kk][0] + row_ * 64 +                            \
            ((hi * 16) ^ (((row_ >> 1) & 3) << 4)));                            \
    }                                                                           \
} while (0)
#define DO_MFMA(mh, afr, bfr) do {                                              \
    __builtin_amdgcn_s_setprio(1);                                              \
    _Pragma("unroll")                                                           \
    for (int i_ = 0; i_ < 4; ++i_)                                              \
        _Pragma("unroll")                                                       \
        for (int n_ = 0; n_ < NF; ++n_)                                         \
            acc[(mh) * 4 + i_][n_] = __builtin_amdgcn_mfma_f32_16x16x32_bf16(   \
                afr[i_], bfr[n_], acc[(mh) * 4 + i_][n_], 0, 0, 0);             \
    __builtin_amdgcn_s_setprio(0);                                              \
} while (0)

    const int NT = K >> 6;

    ISSUE_G1(0, 0);
    ISSUE_G2(0, 0);
    ISSUE_G3(0, 0);
    asm volatile("s_waitcnt vmcnt(%0)" :: "i"(WN) : "memory");  // g1(0) done
    __builtin_amdgcn_s_barrier();

    bf16x8 af[4], bk0[NF], bk1[NF];

    for (int kt = 0; kt < NT; ++kt) {
        const int  b    = kt & 1;
        const int  nb   = b ^ 1;
        const bool last = (kt == NT - 1);

        // ---- P1: quad (mh0, kk0) ----
        if (!last) ISSUE_G1(nb, kt + 1);
        READ_A(b, 0, 0, af);
        READ_B(b, 0, bk0);
        if (last) asm volatile("s_waitcnt vmcnt(0)" ::: "memory");
        else      asm volatile("s_waitcnt vmcnt(%0)" :: "i"(WN) : "memory");
        __builtin_amdgcn_s_barrier();
        DO_MFMA(0, af, bk0);
        __builtin_amdgcn_s_barrier();

        // ---- P2: quad (mh0, kk1) ----
        if (!last) ISSUE_G2(nb, kt + 1);
        READ_A(b, 0, 1, af);
        READ_B(b, 1, bk1);
        __builtin_amdgcn_s_barrier();
        DO_MFMA(0, af, bk1);
        __builtin_amdgcn_s_barrier();

        // ---- P3: quad (mh1, kk1) ----
        if (!last) ISSUE_G3(nb, kt + 1);
        READ_A(b, 1, 1, af);
        __builtin_amdgcn_s_barrier();
        DO_MFMA(1, af, bk1);
        __builtin_amdgcn_s_barrier();

        // ---- P4: quad (mh1, kk0) ----
        READ_A(b, 1, 0, af);
        if (!last) asm volatile("s_waitcnt vmcnt(%0)" :: "i"(WN) : "memory");
        __builtin_amdgcn_s_barrier();
        DO_MFMA(1, af, bk0);
        __builtin_amdgcn_s_barrier();
    }

#pragma unroll
    for (int mf = 0; mf < 8; ++mf)
#pragma unroll
        for (int n = 0; n < NF; ++n)
#pragma unroll
            for (int r = 0; r < 4; ++r) {
                const size_t row = brow + wr * 128 + mf * 16 + hi * 4 + r;
                const size_t col = bcol + wc * (NF * 16) + n * 16 + lr;
                const float v = acc[mf][n][r] + bias[col];
                if (BF16OUT)
                    ((bf16*)out)[row * (size_t)N + col] = (bf16)v;
                else
                    ((float*)out)[row * (size_t)N + col] = v;
            }
#undef STAGE_A_ROUND
#undef STAGE_B_ROUND
#undef ISSUE_G1
#undef ISSUE_G2
#undef ISSUE_G3
#undef READ_A
#undef READ_B
#undef DO_MFMA
}

// ---------------- causal flash attention v3 ----------------
// 128 q-rows/block, 4 waves (32 each), KV tiles of 64, double-buffered K/V,
// async-stage split (K via gload_lds, V via reg prefetch + late scatter),
// interior-tile mask skip, defer-max, setprio. One barrier per tile.
__global__ __launch_bounds__(256) void attn_kernel(const bf16* __restrict__ qkv,
                                                   bf16* __restrict__ o) {
    const int bid = blockIdx.x;
    const int qt  = 15 - (bid >> 6);     // 16 q-tiles; longest first
    const int bh  = bid & 63;
    const int h   = bh & 15;
    const int b   = bh >> 4;
    const int qbase = qt * 128;

    const int tid  = threadIdx.x;
    const int wv   = tid >> 6;
    const int lane = tid & 63;
    const int lr   = lane & 15, hi = lane >> 4;

    __shared__ bf16 Ks[2][64 * 64];       // [buf][k][d], XOR-swizzled rows
    __shared__ bf16 Vt[2][64 * 64];       // [buf][d][k], XOR-swizzled rows
    __shared__ bf16 Pl[4 * 32 * 64];      // per-wave P [q][k], XOR-swizzled rows

    char* Pb = (char*)(Pl + wv * 2048);

    const size_t tokbase = (size_t)b * SEQ;

    // Hoist Q (B-operand of swapped QK^T)
    bf16x8 aq[2][2];
#pragma unroll
    for (int qf = 0; qf < 2; ++qf) {
        const bf16* qg = qkv + (tokbase + qbase + wv * 32 + qf * 16 + lr) * (size_t)QKVF
                         + h * 64;
#pragma unroll
        for (int kk = 0; kk < 2; ++kk)
            aq[qf][kk] = *reinterpret_cast<const bf16x8*>(qg + kk * 32 + hi * 8);
    }

    const f32x4 fzero = {0.f, 0.f, 0.f, 0.f};
    f32x4 oacc[2][4];
#pragma unroll
    for (int qf = 0; qf < 2; ++qf)
#pragma unroll
        for (int n = 0; n < 4; ++n) oacc[qf][n] = fzero;
    float m_r[2] = {-__builtin_inff(), -__builtin_inff()};
    float l_r[2] = {0.f, 0.f};

    const int nkv = qt * 2 + 2;
    const float SC = 0.125f * 1.44269504f; // 1/sqrt(64) * log2(e)

    const int vk0 = tid >> 3;             // V staging: k row
    const int vc  = tid & 7;              // V staging: 16B chunk (d block)
    const int kr8 = lane >> 3;            // K staging helpers
    const int kc8 = (lane & 7) ^ ((lane >> 3) & 7);

#define STAGE_K(dst, kvrow) do {                                                 \
    _Pragma("unroll")                                                            \
    for (int j_ = 0; j_ < 2; ++j_) {                                             \
        const int kr_ = wv * 16 + j_ * 8 + kr8;                                  \
        gload_lds16(qkv + ((kvrow) + kr_) * (size_t)QKVF + EMB + h * 64 + kc8*8, \
                    &(dst)[(wv * 16 + j_ * 8) * 64 + lane * 8]);                 \
    }                                                                            \
} while (0)
#define SCATTER_V(dstb, v0_, v1_) do {                                           \
    _Pragma("unroll")                                                            \
    for (int jj_ = 0; jj_ < 8; ++jj_) {                                          \
        const int d_ = vc * 8 + jj_;                                             \
        char* row_ = (dstb) + d_ * 128;                                          \
        *(bf16*)(row_ + ((vk0 * 2) ^ (vc << 4)))        = v0_[jj_];              \
        *(bf16*)(row_ + (((vk0 + 32) * 2) ^ (vc << 4))) = v1_[jj_];              \
    }                                                                            \
} while (0)

    // prologue: stage tile 0
    {
        STAGE_K(Ks[0], tokbase);
        bf16x8 v0 = *reinterpret_cast<const bf16x8*>(
            qkv + (tokbase + vk0) * (size_t)QKVF + 2 * EMB + h * 64 + vc * 8);
        bf16x8 v1 = *reinterpret_cast<const bf16x8*>(
            qkv + (tokbase + vk0 + 32) * (size_t)QKVF + 2 * EMB + h * 64 + vc * 8);
        SCATTER_V((char*)Vt[0], v0, v1);
    }

    for (int kt = 0; kt < nkv; ++kt) {
        const int bsel = kt & 1;
        char* Ksb = (char*)Ks[bsel];
        char* Vtb = (char*)Vt[bsel];
        __syncthreads();                  // drains my K-gload + V-scatter; all waves aligned

        const bool pf = (kt + 1 < nkv);
        bf16x8 nv0, nv1;
        if (pf) {                         // async-stage split: issue early, consume late
            const size_t nrow = tokbase + (size_t)(kt + 1) * 64;
            STAGE_K(Ks[bsel ^ 1], nrow);
            nv0 = *reinterpret_cast<const bf16x8*>(
                qkv + (nrow + vk0) * (size_t)QKVF + 2 * EMB + h * 64 + vc * 8);
            nv1 = *reinterpret_cast<const bf16x8*>(
                qkv + (nrow + vk0 + 32) * (size_t)QKVF + 2 * EMB + h * 64 + vc * 8);
        }

        // per-qf activity (last tile is above-diagonal for low waves)
        const bool act[2] = { kt * 64 <= qbase + wv * 32 + 15,
                              kt * 64 <= qbase + wv * 32 + 31 };

        // --- S^T = K Q^T : lane holds S[q=qf*16+lr][k=ktile*16+hi*4+r]
        f32x4 s[2][4];
#pragma unroll
        for (int qf = 0; qf < 2; ++qf)
#pragma unroll
            for (int ktile = 0; ktile < 4; ++ktile) s[qf][ktile] = fzero;
        __builtin_amdgcn_s_setprio(1);
#pragma unroll
        for (int ktile = 0; ktile < 4; ++ktile)
#pragma unroll
            for (int kk = 0; kk < 2; ++kk) {
                const int kr = ktile * 16 + lr;
                bf16x8 ak = *reinterpret_cast<const bf16x8*>(
                    Ksb + kr * 128 + ((kk * 64 + hi * 16) ^ ((kr & 7) << 4)));
#pragma unroll
                for (int qf = 0; qf < 2; ++qf)
                    if (act[qf])
                        s[qf][ktile] = __builtin_amdgcn_mfma_f32_16x16x32_bf16(
                            ak, aq[qf][kk], s[qf][ktile], 0, 0, 0);
            }
        __builtin_amdgcn_s_setprio(0);

        // --- scale (+ mask only on diagonal tiles)
#pragma unroll
        for (int qf = 0; qf < 2; ++qf) {
            if (!act[qf]) continue;
            const int qglob = qbase + wv * 32 + qf * 16 + lr;
            const bool interior = (kt * 64 + 63 <= qbase + wv * 32 + qf * 16);
            if (interior) {
#pragma unroll
                for (int ktile = 0; ktile < 4; ++ktile)
#pragma unroll
                    for (int r = 0; r < 4; ++r) s[qf][ktile][r] *= SC;
            } else {
#pragma unroll
                for (int ktile = 0; ktile < 4; ++ktile) {
                    const int kg0 = kt * 64 + ktile * 16 + hi * 4;
#pragma unroll
                    for (int r = 0; r < 4; ++r) {
                        const float sv = s[qf][ktile][r] * SC;
                        s[qf][ktile][r] = (kg0 + r <= qglob) ? sv : -__builtin_inff();
                    }
                }
            }
        }

        // --- online softmax with defer-max
#pragma unroll
        for (int qf = 0; qf < 2; ++qf) {
            if (!act[qf]) continue;
            float tm = s[qf][0][0];
#pragma unroll
            for (int ktile = 0; ktile < 4; ++ktile)
#pragma unroll
                for (int r = 0; r < 4; ++r) tm = fmaxf(tm, s[qf][ktile][r]);
            tm = fmaxf(tm, __shfl_xor(tm, 16));
            tm = fmaxf(tm, __shfl_xor(tm, 32));

            if (__all(tm - m_r[qf] <= 11.5f)) {       // defer: keep old max
                const float mo = m_r[qf];
                float ts = 0.f;
#pragma unroll
                for (int ktile = 0; ktile < 4; ++ktile)
#pragma unroll
                    for (int r = 0; r < 4; ++r) {
                        const float p = __builtin_amdgcn_exp2f(s[qf][ktile][r] - mo);
                        s[qf][ktile][r] = p;
                        ts += p;
                    }
                ts += __shfl_xor(ts, 16);
                ts += __shfl_xor(ts, 32);
                l_r[qf] += ts;
            } else {
                const float mn = fmaxf(m_r[qf], tm);
                const float sc = __builtin_amdgcn_exp2f(m_r[qf] - mn);
                m_r[qf] = mn;
                float ts = 0.f;
#pragma unroll
                for (int ktile = 0; ktile < 4; ++ktile)
#pragma unroll
                    for (int r = 0; r < 4; ++r) {
                        const float p = __builtin_amdgcn_exp2f(s[qf][ktile][r] - mn);
                        s[qf][ktile][r] = p;
                        ts += p;
                    }
                ts += __shfl_xor(ts, 16);
                ts += __shfl_xor(ts, 32);
                l_r[qf] = l_r[qf] * sc + ts;
                float scb[4];
#pragma unroll
                for (int r = 0; r < 4; ++r) scb[r] = __shfl(sc, hi * 4 + r);
#pragma unroll
                for (int n = 0; n < 4; ++n)
#pragma unroll
                    for (int r = 0; r < 4; ++r) oacc[qf][n][r] *= scb[r];
            }

            // write P (bf16) to wave-private LDS, swizzled rows
            const int q = qf * 16 + lr;
#pragma unroll
            for (int ktile = 0; ktile < 4; ++ktile) {
                bf16x4 p4;
#pragma unroll
                for (int r = 0; r < 4; ++r) p4[r] = (bf16)s[qf][ktile][r];
                *(bf16x4*)(Pb + q * 128 + ((ktile * 32 + hi * 8) ^ ((q & 7) << 4))) = p4;
            }
        }

        // --- PV: O += P V
        __builtin_amdgcn_s_setprio(1);
#pragma unroll
        for (int kk = 0; kk < 2; ++kk) {
            bf16x8 ap[2];
#pragma unroll
            for (int qf = 0; qf < 2; ++qf)
                if (act[qf]) {
                    const int q = qf * 16 + lr;
                    ap[qf] = *reinterpret_cast<const bf16x8*>(
                        Pb + q * 128 + ((kk * 64 + hi * 16) ^ ((q & 7) << 4)));
                }
#pragma unroll
            for (int n = 0; n < 4; ++n) {
                const int d = n * 16 + lr;
                bf16x8 bv = *reinterpret_cast<const bf16x8*>(
                    Vtb + d * 128 + ((kk * 64 + hi * 16) ^ (((d >> 3) & 7) << 4)));
#pragma unroll
                for (int qf = 0; qf < 2; ++qf)
                    if (act[qf])
                        oacc[qf][n] = __builtin_amdgcn_mfma_f32_16x16x32_bf16(
                            ap[qf], bv, oacc[qf][n], 0, 0, 0);
            }
        }
        __builtin_amdgcn_s_setprio(0);

        // --- late V scatter for tile kt+1 (off critical path)
        if (pf) SCATTER_V((char*)Vt[bsel ^ 1], nv0, nv1);
    }

    // --- epilogue: normalize and store
#pragma unroll
    for (int qf = 0; qf < 2; ++qf) {
        const float linv = 1.f / l_r[qf];
        float li[4];
#pragma unroll
        for (int r = 0; r < 4; ++r) li[r] = __shfl(linv, hi * 4 + r);
        bf16* og = o + (tokbase + qbase + wv * 32 + qf * 16) * (size_t)EMB + h * 64;
#pragma unroll
        for (int n = 0; n < 4; ++n)
#pragma unroll
            for (int r = 0; r < 4; ++r)
                og[(hi * 4 + r) * (size_t)EMB + n * 16 + lr] =
                    (bf16)(oacc[qf][n][r] * li[r]);
    }
#undef STAGE_K
#undef SCATTER_V
}

// ---------------- launcher ----------------
extern "C" void kernel_launch(void* const* d_in, const int* in_sizes, int n_in,
                              void* d_out, int out_size, void* d_ws, size_t ws_size,
                              hipStream_t stream) {
    const float* x     = (const float*)d_in[0];
    const float* qkv_w = (const float*)d_in[1];
    const float* qkv_b = (const float*)d_in[2];
    const float* out_w = (const float*)d_in[3];
    const float* out_b = (const float*)d_in[4];
    float* out = (float*)d_out;

    char* ws = (char*)d_ws;
    bf16* x_bf    = (bf16*)(ws);                                  // 16 MB
    bf16* qkvw_bf = (bf16*)(ws + 16777216);                       //  6 MB
    bf16* outw_bf = (bf16*)(ws + 23068672);                       //  2 MB
    bf16* qkv_bf  = (bf16*)(ws + 25165824);                       // 48 MB
    bf16* o_bf    = (bf16*)(ws + 75497472);                       // 16 MB

    cvt_f32_bf16<<<8192, 256, 0, stream>>>(x,     x_bf,    NTOK * EMB);
    cvt_f32_bf16<<<3072, 256, 0, stream>>>(qkv_w, qkvw_bf, QKVF * EMB);
    cvt_f32_bf16<<<1024, 256, 0, stream>>>(out_w, outw_bf, EMB * EMB);

    // QKV projection: [8192,1024] x [3072,1024]^T -> bf16 [8192,3072]
    gemm_bt8<4, true><<<(QKVF / 256) * (NTOK / 256), 512, 0, stream>>>(
        x_bf, qkvw_bf, qkv_b, qkv_bf, NTOK, QKVF, EMB);

    // causal attention -> bf16 [8192,1024]
    attn_kernel<<<4 * 16 * (SEQ / 128), 256, 0, stream>>>(qkv_bf, o_bf);

    // output projection: [8192,1024] x [1024,1024]^T -> f32 d_out
    gemm_bt8<2, false><<<(EMB / 128) * (NTOK / 256), 512, 0, stream>>>(
        o_bf, outw_bf, out_b, out, NTOK, EMB, EMB);
}

// Round 5
// 299.076 us; speedup vs baseline: 1.1208x; 1.1208x over previous
//
#include <hip/hip_runtime.h>
#include <hip/hip_bf16.h>
#include <math.h>

// Problem constants (B=4, T=2048, C=1024, H=16, D=64)
#define SEQ   2048
#define NTOK  8192          // B*T
#define EMB   1024
#define QKVF  3072
#define QSCALE 0.18033688f  // 0.125 * log2(e): folded into q-projection

typedef __bf16 bf16;
typedef __bf16 bf16x8 __attribute__((ext_vector_type(8)));
typedef __bf16 bf16x4 __attribute__((ext_vector_type(4)));
typedef float  f32x4  __attribute__((ext_vector_type(4)));

__device__ __forceinline__ void gload_lds16(const bf16* g, bf16* l) {
    __builtin_amdgcn_global_load_lds(
        (const __attribute__((address_space(1))) unsigned int*)g,
        (__attribute__((address_space(3))) unsigned int*)l,
        16, 0, 0);
}

// ---------------- fp32 -> bf16 conversion (vectorized x4) ----------------
__global__ __launch_bounds__(256) void cvt_f32_bf16(const float* __restrict__ in,
                                                    bf16* __restrict__ out, int n) {
    int i = (blockIdx.x * 256 + threadIdx.x) * 4;
    if (i >= n) return;
    float4 f = *reinterpret_cast<const float4*>(in + i);
    bf16x4 o;
    o[0] = (bf16)f.x; o[1] = (bf16)f.y; o[2] = (bf16)f.z; o[3] = (bf16)f.w;
    *reinterpret_cast<bf16x4*>(out + i) = o;
}

// qkv_w conversion with q-rows (first EMB rows = first EMB*EMB elements) pre-scaled
__global__ __launch_bounds__(256) void cvt_qkvw_bf16(const float* __restrict__ in,
                                                     bf16* __restrict__ out) {
    int i = (blockIdx.x * 256 + threadIdx.x) * 4;
    float4 f = *reinterpret_cast<const float4*>(in + i);
    const float s = (i < EMB * EMB) ? QSCALE : 1.f;
    bf16x4 o;
    o[0] = (bf16)(f.x * s); o[1] = (bf16)(f.y * s);
    o[2] = (bf16)(f.z * s); o[3] = (bf16)(f.w * s);
    *reinterpret_cast<bf16x4*>(out + i) = o;
}

// ---------------- bt-GEMM: C[M,N] = A[M,K] * B[N,K]^T + bias ----------------
// m97 128x128 structure + 2-phase double-buffer: stage(t+1) issued BEFORE
// compute(t), ONE __syncthreads per K-step (its vmcnt drain is covered by the
// 32-MFMA compute phase). LDS 64KB -> 2 blocks/CU. XCD-swizzled 1D grid.
template <bool BF16OUT>
__global__ __launch_bounds__(256) void gemm_bt(const bf16* __restrict__ A,
                                               const bf16* __restrict__ Bm,
                                               const float* __restrict__ bias,
                                               void* __restrict__ out,
                                               int M, int N, int K, int scale_cols) {
    __shared__ bf16 As[2][128 * 64];
    __shared__ bf16 Bs[2][128 * 64];

    const int nbx = N >> 7;
    const int q8  = (nbx * (M >> 7)) >> 3;
    const int swz = ((int)blockIdx.x & 7) * q8 + ((int)blockIdx.x >> 3);
    const int bx  = swz % nbx;
    const int by  = swz / nbx;

    const int tid  = threadIdx.x;
    const int lane = tid & 63;
    const int wv   = tid >> 6;
    const int wr   = wv >> 1, wc = wv & 1;
    const int lr   = lane & 15, hi = lane >> 4;
    const size_t brow = (size_t)by * 128;
    const size_t bcol = (size_t)bx * 128;

    const f32x4 fzero = {0.f, 0.f, 0.f, 0.f};
    f32x4 acc[4][4];
#pragma unroll
    for (int m = 0; m < 4; ++m)
#pragma unroll
        for (int n = 0; n < 4; ++n) acc[m][n] = fzero;

    const int r8 = tid >> 3;      // staging row-within-round
    const int c8 = tid & 7;       // staging 16B-column

#define STAGE(buf, kt) do {                                                     \
    _Pragma("unroll")                                                           \
    for (int i_ = 0; i_ < 4; ++i_) {                                            \
        const int row_ = i_ * 32 + r8;                                          \
        const int lin_ = i_ * 256 + tid;                                        \
        gload_lds16(A  + (brow + row_) * (size_t)K + (size_t)(kt) * 64 + c8*8,  \
                    &As[buf][lin_ * 8]);                                        \
        gload_lds16(Bm + (bcol + row_) * (size_t)K + (size_t)(kt) * 64 + c8*8,  \
                    &Bs[buf][lin_ * 8]);                                        \
    }                                                                           \
} while (0)

    const int NT = K >> 6;
    STAGE(0, 0);
    __syncthreads();              // drains prologue staging
    int cur = 0;

    for (int kt = 0; kt < NT; ++kt) {
        if (kt + 1 < NT) STAGE(cur ^ 1, kt + 1);   // issue-early (2-phase)
#pragma unroll
        for (int kk = 0; kk < 2; ++kk) {
            bf16x8 af[4], bfr[4];
#pragma unroll
            for (int m = 0; m < 4; ++m)
                af[m] = *reinterpret_cast<const bf16x8*>(
                    &As[cur][(wr * 64 + m * 16 + lr) * 64 + kk * 32 + hi * 8]);
#pragma unroll
            for (int n = 0; n < 4; ++n)
                bfr[n] = *reinterpret_cast<const bf16x8*>(
                    &Bs[cur][(wc * 64 + n * 16 + lr) * 64 + kk * 32 + hi * 8]);
#pragma unroll
            for (int m = 0; m < 4; ++m)
#pragma unroll
                for (int n = 0; n < 4; ++n)
                    acc[m][n] = __builtin_amdgcn_mfma_f32_16x16x32_bf16(
                        af[m], bfr[n], acc[m][n], 0, 0, 0);
        }
        __syncthreads();          // single drain point per K-step (covered by MFMA)
        cur ^= 1;
    }

#pragma unroll
    for (int m = 0; m < 4; ++m)
#pragma unroll
        for (int n = 0; n < 4; ++n)
#pragma unroll
            for (int r = 0; r < 4; ++r) {
                const size_t row = brow + wr * 64 + m * 16 + hi * 4 + r;
                const size_t col = bcol + wc * 64 + n * 16 + lr;
                const float bb = bias[col];
                const float v = acc[m][n][r] + (((int)col < scale_cols) ? bb * QSCALE : bb);
                if (BF16OUT)
                    ((bf16*)out)[row * (size_t)N + col] = (bf16)v;
                else
                    ((float*)out)[row * (size_t)N + col] = v;
            }
#undef STAGE
}

// ---------------- causal flash attention (v2 base + pre-scaled Q + mask skip +
// tree reductions) ----------------
// 128 q-rows/block, 4 waves (32 each), KV tiles of 64, single-buffered.
__global__ __launch_bounds__(256) void attn_kernel(const bf16* __restrict__ qkv,
                                                   bf16* __restrict__ o) {
    const int bid = blockIdx.x;
    const int qt  = 15 - (bid >> 6);     // 16 q-tiles; longest first
    const int bh  = bid & 63;
    const int h   = bh & 15;
    const int b   = bh >> 4;
    const int qbase = qt * 128;

    const int tid  = threadIdx.x;
    const int wv   = tid >> 6;
    const int lane = tid & 63;
    const int lr   = lane & 15, hi = lane >> 4;

    __shared__ bf16 Ks[64 * 64];          // K tile [k][d], XOR-swizzled rows
    __shared__ bf16 Vt[64 * 64];          // V^T tile [d][k], XOR-swizzled rows
    __shared__ bf16 Pl[4 * 32 * 64];      // per-wave P [q][k], XOR-swizzled rows

    char* Ksb = (char*)Ks;
    char* Vtb = (char*)Vt;
    char* Pb  = (char*)(Pl + wv * 2048);

    const size_t tokbase = (size_t)b * SEQ;

    // Hoist Q (B-operand of swapped QK^T); Q already carries 0.125*log2e
    bf16x8 aq[2][2];
#pragma unroll
    for (int qf = 0; qf < 2; ++qf) {
        const bf16* qg = qkv + (tokbase + qbase + wv * 32 + qf * 16 + lr) * (size_t)QKVF
                         + h * 64;
#pragma unroll
        for (int kk = 0; kk < 2; ++kk)
            aq[qf][kk] = *reinterpret_cast<const bf16x8*>(qg + kk * 32 + hi * 8);
    }

    const f32x4 fzero = {0.f, 0.f, 0.f, 0.f};
    f32x4 oacc[2][4];
#pragma unroll
    for (int qf = 0; qf < 2; ++qf)
#pragma unroll
        for (int n = 0; n < 4; ++n) oacc[qf][n] = fzero;
    float m_r[2] = {-__builtin_inff(), -__builtin_inff()};
    float l_r[2] = {0.f, 0.f};

    const int nkv = qt * 2 + 2;

    const int vk0 = tid >> 3;
    const int vc  = tid & 7;

    for (int kt = 0; kt < nkv; ++kt) {
        const size_t kvrow = tokbase + (size_t)kt * 64;
        __syncthreads();

        // --- stage K [64][64] via global_load_lds, pre-swizzled source
#pragma unroll
        for (int j = 0; j < 2; ++j) {
            const int kr = wv * 16 + j * 8 + (lane >> 3);
            const int cg = (lane & 7) ^ ((lane >> 3) & 7);
            gload_lds16(qkv + (kvrow + kr) * (size_t)QKVF + EMB + h * 64 + cg * 8,
                        &Ks[(wv * 16 + j * 8) * 64 + lane * 8]);
        }

        // --- stage V transposed: Vt[d][k], byte = d*128 + ((2k) ^ ((d>>3)&7)<<4)
        {
            bf16x8 v0 = *reinterpret_cast<const bf16x8*>(
                qkv + (kvrow + vk0) * (size_t)QKVF + 2 * EMB + h * 64 + vc * 8);
            bf16x8 v1 = *reinterpret_cast<const bf16x8*>(
                qkv + (kvrow + vk0 + 32) * (size_t)QKVF + 2 * EMB + h * 64 + vc * 8);
#pragma unroll
            for (int jj = 0; jj < 8; ++jj) {
                const int d = vc * 8 + jj;
                char* row = Vtb + d * 128;
                *(bf16*)(row + ((vk0 * 2) ^ (vc << 4)))        = v0[jj];
                *(bf16*)(row + (((vk0 + 32) * 2) ^ (vc << 4))) = v1[jj];
            }
        }
        __syncthreads();

        // --- S^T = K Q^T : lane holds S[q=qf*16+lr][k=ktile*16+hi*4+r]
        f32x4 s[2][4];
#pragma unroll
        for (int qf = 0; qf < 2; ++qf)
#pragma unroll
            for (int ktile = 0; ktile < 4; ++ktile) s[qf][ktile] = fzero;
#pragma unroll
        for (int ktile = 0; ktile < 4; ++ktile)
#pragma unroll
            for (int kk = 0; kk < 2; ++kk) {
                const int kr = ktile * 16 + lr;
                bf16x8 ak = *reinterpret_cast<const bf16x8*>(
                    Ksb + kr * 128 + ((kk * 64 + hi * 16) ^ ((kr & 7) << 4)));
#pragma unroll
                for (int qf = 0; qf < 2; ++qf)
                    s[qf][ktile] = __builtin_amdgcn_mfma_f32_16x16x32_bf16(
                        ak, aq[qf][kk], s[qf][ktile], 0, 0, 0);
            }

        // --- causal mask: only on non-interior (diagonal) tiles; wave-uniform branch
#pragma unroll
        for (int qf = 0; qf < 2; ++qf) {
            if (kt * 64 + 63 > qbase + wv * 32 + qf * 16) {
                const int qglob = qbase + wv * 32 + qf * 16 + lr;
#pragma unroll
                for (int ktile = 0; ktile < 4; ++ktile) {
                    const int kg0 = kt * 64 + ktile * 16 + hi * 4;
#pragma unroll
                    for (int r = 0; r < 4; ++r)
                        if (kg0 + r > qglob) s[qf][ktile][r] = -__builtin_inff();
                }
            }
        }

        // --- online softmax (tree reductions; rows pre-scaled into exp2 domain)
#pragma unroll
        for (int qf = 0; qf < 2; ++qf) {
            float t4[4];
#pragma unroll
            for (int ktile = 0; ktile < 4; ++ktile)
                t4[ktile] = fmaxf(fmaxf(s[qf][ktile][0], s[qf][ktile][1]),
                                  fmaxf(s[qf][ktile][2], s[qf][ktile][3]));
            float tm = fmaxf(fmaxf(t4[0], t4[1]), fmaxf(t4[2], t4[3]));
            tm = fmaxf(tm, __shfl_xor(tm, 16));
            tm = fmaxf(tm, __shfl_xor(tm, 32));

            const float mn = fmaxf(m_r[qf], tm);
            const float sc = __builtin_amdgcn_exp2f(m_r[qf] - mn);
            m_r[qf] = mn;

            float s4[4];
#pragma unroll
            for (int ktile = 0; ktile < 4; ++ktile) {
                float p0 = __builtin_amdgcn_exp2f(s[qf][ktile][0] - mn);
                float p1 = __builtin_amdgcn_exp2f(s[qf][ktile][1] - mn);
                float p2 = __builtin_amdgcn_exp2f(s[qf][ktile][2] - mn);
                float p3 = __builtin_amdgcn_exp2f(s[qf][ktile][3] - mn);
                s[qf][ktile][0] = p0; s[qf][ktile][1] = p1;
                s[qf][ktile][2] = p2; s[qf][ktile][3] = p3;
                s4[ktile] = (p0 + p1) + (p2 + p3);
            }
            float ts = (s4[0] + s4[1]) + (s4[2] + s4[3]);
            ts += __shfl_xor(ts, 16);
            ts += __shfl_xor(ts, 32);
            l_r[qf] = l_r[qf] * sc + ts;

            // broadcast rescale factors into C layout (row = hi*4+r)
            float scb[4];
#pragma unroll
            for (int r = 0; r < 4; ++r) scb[r] = __shfl(sc, hi * 4 + r);
#pragma unroll
            for (int n = 0; n < 4; ++n)
#pragma unroll
                for (int r = 0; r < 4; ++r) oacc[qf][n][r] *= scb[r];

            // write P (bf16) to wave-private LDS, swizzled rows
            const int q = qf * 16 + lr;
#pragma unroll
            for (int ktile = 0; ktile < 4; ++ktile) {
                bf16x4 p4;
#pragma unroll
                for (int r = 0; r < 4; ++r) p4[r] = (bf16)s[qf][ktile][r];
                *(bf16x4*)(Pb + q * 128 + ((ktile * 32 + hi * 8) ^ ((q & 7) << 4))) = p4;
            }
        }

        // --- PV: O += P V
#pragma unroll
        for (int kk = 0; kk < 2; ++kk) {
            bf16x8 ap[2];
#pragma unroll
            for (int qf = 0; qf < 2; ++qf) {
                const int q = qf * 16 + lr;
                ap[qf] = *reinterpret_cast<const bf16x8*>(
                    Pb + q * 128 + ((kk * 64 + hi * 16) ^ ((q & 7) << 4)));
            }
#pragma unroll
            for (int n = 0; n < 4; ++n) {
                const int d = n * 16 + lr;
                bf16x8 bv = *reinterpret_cast<const bf16x8*>(
                    Vtb + d * 128 + ((kk * 64 + hi * 16) ^ (((d >> 3) & 7) << 4)));
#pragma unroll
                for (int qf = 0; qf < 2; ++qf)
                    oacc[qf][n] = __builtin_amdgcn_mfma_f32_16x16x32_bf16(
                        ap[qf], bv, oacc[qf][n], 0, 0, 0);
            }
        }
    }

    // --- epilogue: normalize and store
#pragma unroll
    for (int qf = 0; qf < 2; ++qf) {
        const float linv = 1.f / l_r[qf];
        float li[4];
#pragma unroll
        for (int r = 0; r < 4; ++r) li[r] = __shfl(linv, hi * 4 + r);
        bf16* og = o + (tokbase + qbase + wv * 32 + qf * 16) * (size_t)EMB + h * 64;
#pragma unroll
        for (int n = 0; n < 4; ++n)
#pragma unroll
            for (int r = 0; r < 4; ++r)
                og[(hi * 4 + r) * (size_t)EMB + n * 16 + lr] =
                    (bf16)(oacc[qf][n][r] * li[r]);
    }
}

// ---------------- launcher ----------------
extern "C" void kernel_launch(void* const* d_in, const int* in_sizes, int n_in,
                              void* d_out, int out_size, void* d_ws, size_t ws_size,
                              hipStream_t stream) {
    const float* x     = (const float*)d_in[0];
    const float* qkv_w = (const float*)d_in[1];
    const float* qkv_b = (const float*)d_in[2];
    const float* out_w = (const float*)d_in[3];
    const float* out_b = (const float*)d_in[4];
    float* out = (float*)d_out;

    char* ws = (char*)d_ws;
    bf16* x_bf    = (bf16*)(ws);                                  // 16 MB
    bf16* qkvw_bf = (bf16*)(ws + 16777216);                       //  6 MB
    bf16* outw_bf = (bf16*)(ws + 23068672);                       //  2 MB
    bf16* qkv_bf  = (bf16*)(ws + 25165824);                       // 48 MB
    bf16* o_bf    = (bf16*)(ws + 75497472);                       // 16 MB

    cvt_f32_bf16<<<8192, 256, 0, stream>>>(x,     x_bf,    NTOK * EMB);
    cvt_qkvw_bf16<<<3072, 256, 0, stream>>>(qkv_w, qkvw_bf);
    cvt_f32_bf16<<<1024, 256, 0, stream>>>(out_w, outw_bf, EMB * EMB);

    // QKV projection: [8192,1024] x [3072,1024]^T -> bf16 [8192,3072]
    // grid 1536 = 6 * 256 CUs exactly; q-cols' bias scaled in epilogue
    gemm_bt<true><<<(QKVF / 128) * (NTOK / 128), 256, 0, stream>>>(
        x_bf, qkvw_bf, qkv_b, qkv_bf, NTOK, QKVF, EMB, EMB);

    // causal attention -> bf16 [8192,1024]
    attn_kernel<<<4 * 16 * (SEQ / 128), 256, 0, stream>>>(qkv_bf, o_bf);

    // output projection: [8192,1024] x [1024,1024]^T -> f32 d_out (grid 512)
    gemm_bt<false><<<(EMB / 128) * (NTOK / 128), 256, 0, stream>>>(
        o_bf, outw_bf, out_b, out, NTOK, EMB, EMB, 0);
}

// Round 6
// 292.701 us; speedup vs baseline: 1.1452x; 1.0218x over previous
//
#include <hip/hip_runtime.h>
#include <hip/hip_bf16.h>
#include <math.h>

// Problem constants (B=4, T=2048, C=1024, H=16, D=64)
#define SEQ   2048
#define NTOK  8192          // B*T
#define EMB   1024
#define QKVF  3072
#define QSCALE 0.18033688f  // 0.125 * log2(e): folded into q-projection

typedef __bf16 bf16;
typedef __bf16 bf16x8 __attribute__((ext_vector_type(8)));
typedef __bf16 bf16x4 __attribute__((ext_vector_type(4)));
typedef unsigned short u16x8 __attribute__((ext_vector_type(8)));
typedef float  f32x4  __attribute__((ext_vector_type(4)));

__device__ __forceinline__ void gload_lds16(const bf16* g, bf16* l) {
    __builtin_amdgcn_global_load_lds(
        (const __attribute__((address_space(1))) unsigned int*)g,
        (__attribute__((address_space(3))) unsigned int*)l,
        16, 0, 0);
}

// ---------------- fp32 -> bf16 conversion (vectorized x4) ----------------
__global__ __launch_bounds__(256) void cvt_f32_bf16(const float* __restrict__ in,
                                                    bf16* __restrict__ out, int n) {
    int i = (blockIdx.x * 256 + threadIdx.x) * 4;
    if (i >= n) return;
    float4 f = *reinterpret_cast<const float4*>(in + i);
    bf16x4 o;
    o[0] = (bf16)f.x; o[1] = (bf16)f.y; o[2] = (bf16)f.z; o[3] = (bf16)f.w;
    *reinterpret_cast<bf16x4*>(out + i) = o;
}

// qkv_w conversion with q-rows (first EMB*EMB elements) pre-scaled by QSCALE
__global__ __launch_bounds__(256) void cvt_qkvw_bf16(const float* __restrict__ in,
                                                     bf16* __restrict__ out) {
    int i = (blockIdx.x * 256 + threadIdx.x) * 4;
    float4 f = *reinterpret_cast<const float4*>(in + i);
    const float s = (i < EMB * EMB) ? QSCALE : 1.f;
    bf16x4 o;
    o[0] = (bf16)(f.x * s); o[1] = (bf16)(f.y * s);
    o[2] = (bf16)(f.z * s); o[3] = (bf16)(f.w * s);
    *reinterpret_cast<bf16x4*>(out + i) = o;
}

// ---------------- bt-GEMM: C[M,N] = A[M,K] * B[N,K]^T + bias ----------------
// m97 128x128 structure + 2-phase double-buffer with COUNTED vmcnt (T4):
// stage(t+1) stays in flight across both barriers; no vmcnt(0) drain in the
// main loop. LDS 64KB -> 2 blocks/CU. XCD-swizzled 1D grid.
template <bool BF16OUT>
__global__ __launch_bounds__(256) void gemm_bt(const bf16* __restrict__ A,
                                               const bf16* __restrict__ Bm,
                                               const float* __restrict__ bias,
                                               void* __restrict__ out,
                                               int M, int N, int K, int scale_cols) {
    __shared__ bf16 As[2][128 * 64];
    __shared__ bf16 Bs[2][128 * 64];

    const int nbx = N >> 7;
    const int q8  = (nbx * (M >> 7)) >> 3;
    const int swz = ((int)blockIdx.x & 7) * q8 + ((int)blockIdx.x >> 3);
    const int bx  = swz % nbx;
    const int by  = swz / nbx;

    const int tid  = threadIdx.x;
    const int lane = tid & 63;
    const int wv   = tid >> 6;
    const int wr   = wv >> 1, wc = wv & 1;
    const int lr   = lane & 15, hi = lane >> 4;
    const size_t brow = (size_t)by * 128;
    const size_t bcol = (size_t)bx * 128;

    const f32x4 fzero = {0.f, 0.f, 0.f, 0.f};
    f32x4 acc[4][4];
#pragma unroll
    for (int m = 0; m < 4; ++m)
#pragma unroll
        for (int n = 0; n < 4; ++n) acc[m][n] = fzero;

    const int r8 = tid >> 3;      // staging row-within-round
    const int c8 = tid & 7;       // staging 16B-column

#define STAGE(buf, kt) do {                                                     \
    _Pragma("unroll")                                                           \
    for (int i_ = 0; i_ < 4; ++i_) {                                            \
        const int row_ = i_ * 32 + r8;                                          \
        const int lin_ = i_ * 256 + tid;                                        \
        gload_lds16(A  + (brow + row_) * (size_t)K + (size_t)(kt) * 64 + c8*8,  \
                    &As[buf][lin_ * 8]);                                        \
        gload_lds16(Bm + (bcol + row_) * (size_t)K + (size_t)(kt) * 64 + c8*8,  \
                    &Bs[buf][lin_ * 8]);                                        \
    }                                                                           \
} while (0)

    const int NT = K >> 6;
    STAGE(0, 0);                  // 8 loads in flight
    int cur = 0;

    for (int kt = 0; kt < NT; ++kt) {
        if (kt + 1 < NT) {
            STAGE(cur ^ 1, kt + 1);                              // +8 in flight
            asm volatile("s_waitcnt vmcnt(8)" ::: "memory");     // buf[cur] landed
        } else {
            asm volatile("s_waitcnt vmcnt(0)" ::: "memory");
        }
        __builtin_amdgcn_s_barrier();    // all waves' buf[cur] staged

#pragma unroll
        for (int kk = 0; kk < 2; ++kk) {
            bf16x8 af[4], bfr[4];
#pragma unroll
            for (int m = 0; m < 4; ++m)
                af[m] = *reinterpret_cast<const bf16x8*>(
                    &As[cur][(wr * 64 + m * 16 + lr) * 64 + kk * 32 + hi * 8]);
#pragma unroll
            for (int n = 0; n < 4; ++n)
                bfr[n] = *reinterpret_cast<const bf16x8*>(
                    &Bs[cur][(wc * 64 + n * 16 + lr) * 64 + kk * 32 + hi * 8]);
#pragma unroll
            for (int m = 0; m < 4; ++m)
#pragma unroll
                for (int n = 0; n < 4; ++n)
                    acc[m][n] = __builtin_amdgcn_mfma_f32_16x16x32_bf16(
                        af[m], bfr[n], acc[m][n], 0, 0, 0);
        }

        asm volatile("s_waitcnt lgkmcnt(0)" ::: "memory");  // my reads of buf[cur] done
        __builtin_amdgcn_s_barrier();                       // everyone's reads done
        cur ^= 1;
    }

#pragma unroll
    for (int m = 0; m < 4; ++m)
#pragma unroll
        for (int n = 0; n < 4; ++n)
#pragma unroll
            for (int r = 0; r < 4; ++r) {
                const size_t row = brow + wr * 64 + m * 16 + hi * 4 + r;
                const size_t col = bcol + wc * 64 + n * 16 + lr;
                const float bb = bias[col];
                const float v = acc[m][n][r] + (((int)col < scale_cols) ? bb * QSCALE : bb);
                if (BF16OUT)
                    ((bf16*)out)[row * (size_t)N + col] = (bf16)v;
                else
                    ((float*)out)[row * (size_t)N + col] = v;
            }
#undef STAGE
}

// ---------------- causal flash attention ----------------
// 128 q-rows/block, 4 waves (32 each), KV tiles of 64, single-buffered.
// V-scatter: k-pair remap -> 8 x ds_write_b32 per lane (was 16 x ds_write_b16).
__global__ __launch_bounds__(256) void attn_kernel(const bf16* __restrict__ qkv,
                                                   bf16* __restrict__ o) {
    const int bid = blockIdx.x;
    const int qt  = 15 - (bid >> 6);     // 16 q-tiles; longest first
    const int bh  = bid & 63;
    const int h   = bh & 15;
    const int b   = bh >> 4;
    const int qbase = qt * 128;

    const int tid  = threadIdx.x;
    const int wv   = tid >> 6;
    const int lane = tid & 63;
    const int lr   = lane & 15, hi = lane >> 4;

    __shared__ bf16 Ks[64 * 64];          // K tile [k][d], XOR-swizzled rows
    __shared__ bf16 Vt[64 * 64];          // V^T tile [d][k], XOR-swizzled rows
    __shared__ bf16 Pl[4 * 32 * 64];      // per-wave P [q][k], XOR-swizzled rows

    char* Ksb = (char*)Ks;
    char* Vtb = (char*)Vt;
    char* Pb  = (char*)(Pl + wv * 2048);

    const size_t tokbase = (size_t)b * SEQ;

    // Hoist Q (B-operand of swapped QK^T); Q already carries 0.125*log2e
    bf16x8 aq[2][2];
#pragma unroll
    for (int qf = 0; qf < 2; ++qf) {
        const bf16* qg = qkv + (tokbase + qbase + wv * 32 + qf * 16 + lr) * (size_t)QKVF
                         + h * 64;
#pragma unroll
        for (int kk = 0; kk < 2; ++kk)
            aq[qf][kk] = *reinterpret_cast<const bf16x8*>(qg + kk * 32 + hi * 8);
    }

    const f32x4 fzero = {0.f, 0.f, 0.f, 0.f};
    f32x4 oacc[2][4];
#pragma unroll
    for (int qf = 0; qf < 2; ++qf)
#pragma unroll
        for (int n = 0; n < 4; ++n) oacc[qf][n] = fzero;
    float m_r[2] = {-__builtin_inff(), -__builtin_inff()};
    float l_r[2] = {0.f, 0.f};

    const int nkv = qt * 2 + 2;

    const int kp = tid >> 3;              // V staging: k-pair index (k = 2kp, 2kp+1)
    const int vc = tid & 7;               // V staging: 16B d-chunk

    for (int kt = 0; kt < nkv; ++kt) {
        const size_t kvrow = tokbase + (size_t)kt * 64;
        __syncthreads();

        // --- stage K [64][64] via global_load_lds, pre-swizzled source
#pragma unroll
        for (int j = 0; j < 2; ++j) {
            const int kr = wv * 16 + j * 8 + (lane >> 3);
            const int cg = (lane & 7) ^ ((lane >> 3) & 7);
            gload_lds16(qkv + (kvrow + kr) * (size_t)QKVF + EMB + h * 64 + cg * 8,
                        &Ks[(wv * 16 + j * 8) * 64 + lane * 8]);
        }

        // --- stage V transposed: adjacent k-pair -> packed b32 writes
        {
            const bf16* vg = qkv + (kvrow + 2 * kp) * (size_t)QKVF + 2 * EMB + h * 64 + vc * 8;
            u16x8 v0 = *reinterpret_cast<const u16x8*>(vg);
            u16x8 v1 = *reinterpret_cast<const u16x8*>(vg + QKVF);
#pragma unroll
            for (int jj = 0; jj < 8; ++jj) {
                const int d = vc * 8 + jj;
                const unsigned int pr = (unsigned int)v0[jj] | ((unsigned int)v1[jj] << 16);
                *(unsigned int*)(Vtb + d * 128 + ((4 * kp) ^ (vc << 4))) = pr;
            }
        }
        __syncthreads();

        // --- S^T = K Q^T : lane holds S[q=qf*16+lr][k=ktile*16+hi*4+r]
        f32x4 s[2][4];
#pragma unroll
        for (int qf = 0; qf < 2; ++qf)
#pragma unroll
            for (int ktile = 0; ktile < 4; ++ktile) s[qf][ktile] = fzero;
#pragma unroll
        for (int ktile = 0; ktile < 4; ++ktile)
#pragma unroll
            for (int kk = 0; kk < 2; ++kk) {
                const int kr = ktile * 16 + lr;
                bf16x8 ak = *reinterpret_cast<const bf16x8*>(
                    Ksb + kr * 128 + ((kk * 64 + hi * 16) ^ ((kr & 7) << 4)));
#pragma unroll
                for (int qf = 0; qf < 2; ++qf)
                    s[qf][ktile] = __builtin_amdgcn_mfma_f32_16x16x32_bf16(
                        ak, aq[qf][kk], s[qf][ktile], 0, 0, 0);
            }

        // --- causal mask: only on non-interior (diagonal) tiles; wave-uniform branch
#pragma unroll
        for (int qf = 0; qf < 2; ++qf) {
            if (kt * 64 + 63 > qbase + wv * 32 + qf * 16) {
                const int qglob = qbase + wv * 32 + qf * 16 + lr;
#pragma unroll
                for (int ktile = 0; ktile < 4; ++ktile) {
                    const int kg0 = kt * 64 + ktile * 16 + hi * 4;
#pragma unroll
                    for (int r = 0; r < 4; ++r)
                        if (kg0 + r > qglob) s[qf][ktile][r] = -__builtin_inff();
                }
            }
        }

        // --- online softmax (tree reductions; scores pre-scaled into exp2 domain)
#pragma unroll
        for (int qf = 0; qf < 2; ++qf) {
            float t4[4];
#pragma unroll
            for (int ktile = 0; ktile < 4; ++ktile)
                t4[ktile] = fmaxf(fmaxf(s[qf][ktile][0], s[qf][ktile][1]),
                                  fmaxf(s[qf][ktile][2], s[qf][ktile][3]));
            float tm = fmaxf(fmaxf(t4[0], t4[1]), fmaxf(t4[2], t4[3]));
            tm = fmaxf(tm, __shfl_xor(tm, 16));
            tm = fmaxf(tm, __shfl_xor(tm, 32));

            const float mn = fmaxf(m_r[qf], tm);
            const float sc = __builtin_amdgcn_exp2f(m_r[qf] - mn);
            m_r[qf] = mn;

            float s4[4];
#pragma unroll
            for (int ktile = 0; ktile < 4; ++ktile) {
                float p0 = __builtin_amdgcn_exp2f(s[qf][ktile][0] - mn);
                float p1 = __builtin_amdgcn_exp2f(s[qf][ktile][1] - mn);
                float p2 = __builtin_amdgcn_exp2f(s[qf][ktile][2] - mn);
                float p3 = __builtin_amdgcn_exp2f(s[qf][ktile][3] - mn);
                s[qf][ktile][0] = p0; s[qf][ktile][1] = p1;
                s[qf][ktile][2] = p2; s[qf][ktile][3] = p3;
                s4[ktile] = (p0 + p1) + (p2 + p3);
            }
            float ts = (s4[0] + s4[1]) + (s4[2] + s4[3]);
            ts += __shfl_xor(ts, 16);
            ts += __shfl_xor(ts, 32);
            l_r[qf] = l_r[qf] * sc + ts;

            // broadcast rescale factors into C layout (row = hi*4+r)
            float scb[4];
#pragma unroll
            for (int r = 0; r < 4; ++r) scb[r] = __shfl(sc, hi * 4 + r);
#pragma unroll
            for (int n = 0; n < 4; ++n)
#pragma unroll
                for (int r = 0; r < 4; ++r) oacc[qf][n][r] *= scb[r];

            // write P (bf16) to wave-private LDS, swizzled rows
            const int q = qf * 16 + lr;
#pragma unroll
            for (int ktile = 0; ktile < 4; ++ktile) {
                bf16x4 p4;
#pragma unroll
                for (int r = 0; r < 4; ++r) p4[r] = (bf16)s[qf][ktile][r];
                *(bf16x4*)(Pb + q * 128 + ((ktile * 32 + hi * 8) ^ ((q & 7) << 4))) = p4;
            }
        }

        // --- PV: O += P V
#pragma unroll
        for (int kk = 0; kk < 2; ++kk) {
            bf16x8 ap[2];
#pragma unroll
            for (int qf = 0; qf < 2; ++qf) {
                const int q = qf * 16 + lr;
                ap[qf] = *reinterpret_cast<const bf16x8*>(
                    Pb + q * 128 + ((kk * 64 + hi * 16) ^ ((q & 7) << 4)));
            }
#pragma unroll
            for (int n = 0; n < 4; ++n) {
                const int d = n * 16 + lr;
                bf16x8 bv = *reinterpret_cast<const bf16x8*>(
                    Vtb + d * 128 + ((kk * 64 + hi * 16) ^ (((d >> 3) & 7) << 4)));
#pragma unroll
                for (int qf = 0; qf < 2; ++qf)
                    oacc[qf][n] = __builtin_amdgcn_mfma_f32_16x16x32_bf16(
                        ap[qf], bv, oacc[qf][n], 0, 0, 0);
            }
        }
    }

    // --- epilogue: normalize and store
#pragma unroll
    for (int qf = 0; qf < 2; ++qf) {
        const float linv = 1.f / l_r[qf];
        float li[4];
#pragma unroll
        for (int r = 0; r < 4; ++r) li[r] = __shfl(linv, hi * 4 + r);
        bf16* og = o + (tokbase + qbase + wv * 32 + qf * 16) * (size_t)EMB + h * 64;
#pragma unroll
        for (int n = 0; n < 4; ++n)
#pragma unroll
            for (int r = 0; r < 4; ++r)
                og[(hi * 4 + r) * (size_t)EMB + n * 16 + lr] =
                    (bf16)(oacc[qf][n][r] * li[r]);
    }
}

// ---------------- launcher ----------------
extern "C" void kernel_launch(void* const* d_in, const int* in_sizes, int n_in,
                              void* d_out, int out_size, void* d_ws, size_t ws_size,
                              hipStream_t stream) {
    const float* x     = (const float*)d_in[0];
    const float* qkv_w = (const float*)d_in[1];
    const float* qkv_b = (const float*)d_in[2];
    const float* out_w = (const float*)d_in[3];
    const float* out_b = (const float*)d_in[4];
    float* out = (float*)d_out;

    char* ws = (char*)d_ws;
    bf16* x_bf    = (bf16*)(ws);                                  // 16 MB
    bf16* qkvw_bf = (bf16*)(ws + 16777216);                       //  6 MB
    bf16* outw_bf = (bf16*)(ws + 23068672);                       //  2 MB
    bf16* qkv_bf  = (bf16*)(ws + 25165824);                       // 48 MB
    bf16* o_bf    = (bf16*)(ws + 75497472);                       // 16 MB

    cvt_f32_bf16<<<8192, 256, 0, stream>>>(x,     x_bf,    NTOK * EMB);
    cvt_qkvw_bf16<<<3072, 256, 0, stream>>>(qkv_w, qkvw_bf);
    cvt_f32_bf16<<<1024, 256, 0, stream>>>(out_w, outw_bf, EMB * EMB);

    // QKV projection: [8192,1024] x [3072,1024]^T -> bf16 [8192,3072]
    gemm_bt<true><<<(QKVF / 128) * (NTOK / 128), 256, 0, stream>>>(
        x_bf, qkvw_bf, qkv_b, qkv_bf, NTOK, QKVF, EMB, EMB);

    // causal attention -> bf16 [8192,1024]
    attn_kernel<<<4 * 16 * (SEQ / 128), 256, 0, stream>>>(qkv_bf, o_bf);

    // output projection: [8192,1024] x [1024,1024]^T -> f32 d_out
    gemm_bt<false><<<(EMB / 128) * (NTOK / 128), 256, 0, stream>>>(
        o_bf, outw_bf, out_b, out, NTOK, EMB, EMB, 0);
}

// Round 7
// 288.137 us; speedup vs baseline: 1.1633x; 1.0158x over previous
//
#include <hip/hip_runtime.h>
#include <hip/hip_bf16.h>
#include <math.h>

// Problem constants (B=4, T=2048, C=1024, H=16, D=64)
#define SEQ   2048
#define NTOK  8192          // B*T
#define EMB   1024
#define QKVF  3072
#define QSCALE 0.18033688f  // 0.125 * log2(e): folded into q-projection

typedef __bf16 bf16;
typedef __bf16 bf16x8 __attribute__((ext_vector_type(8)));
typedef __bf16 bf16x4 __attribute__((ext_vector_type(4)));
typedef unsigned short u16x8 __attribute__((ext_vector_type(8)));
typedef float  f32x4  __attribute__((ext_vector_type(4)));

__device__ __forceinline__ void gload_lds16(const bf16* g, bf16* l) {
    __builtin_amdgcn_global_load_lds(
        (const __attribute__((address_space(1))) unsigned int*)g,
        (__attribute__((address_space(3))) unsigned int*)l,
        16, 0, 0);
}

// ---------------- fp32 -> bf16 conversion (vectorized x4) ----------------
__global__ __launch_bounds__(256) void cvt_f32_bf16(const float* __restrict__ in,
                                                    bf16* __restrict__ out, int n) {
    int i = (blockIdx.x * 256 + threadIdx.x) * 4;
    if (i >= n) return;
    float4 f = *reinterpret_cast<const float4*>(in + i);
    bf16x4 o;
    o[0] = (bf16)f.x; o[1] = (bf16)f.y; o[2] = (bf16)f.z; o[3] = (bf16)f.w;
    *reinterpret_cast<bf16x4*>(out + i) = o;
}

// qkv_w conversion with q-rows (first EMB*EMB elements) pre-scaled by QSCALE
__global__ __launch_bounds__(256) void cvt_qkvw_bf16(const float* __restrict__ in,
                                                     bf16* __restrict__ out) {
    int i = (blockIdx.x * 256 + threadIdx.x) * 4;
    float4 f = *reinterpret_cast<const float4*>(in + i);
    const float s = (i < EMB * EMB) ? QSCALE : 1.f;
    bf16x4 o;
    o[0] = (bf16)(f.x * s); o[1] = (bf16)(f.y * s);
    o[2] = (bf16)(f.z * s); o[3] = (bf16)(f.w * s);
    *reinterpret_cast<bf16x4*>(out + i) = o;
}

// ---------------- 8-wave bt-GEMM: C[M,N] = A[M,K]*B[N,K]^T + bias ----------
// BM = WR*64, BN = WC*64 (WR*WC = 8 waves, 512 threads), BK=64.
// 2-phase double-buffer + counted vmcnt; T2 XOR swizzle (pre-swizzled global
// source, swizzled ds_read). LDS = (BM+BN)*64*2B*2buf = 96KB -> 1 block/CU.
template <int WR, int WC, bool BF16OUT>
__global__ __launch_bounds__(512, 2) void gemm_bt8(const bf16* __restrict__ A,
                                                   const bf16* __restrict__ Bm,
                                                   const float* __restrict__ bias,
                                                   void* __restrict__ out,
                                                   int M, int N, int K, int scale_cols) {
    constexpr int BM = WR * 64, BN = WC * 64;
    constexpr int WN = WR + WC;           // loads/thread/K-step (= counted vmcnt)
    __shared__ bf16 As[2][BM * 64];
    __shared__ bf16 Bs[2][BN * 64];

    const int nbx = N / BN;
    const int q8  = (nbx * (M / BM)) >> 3;
    const int swz = ((int)blockIdx.x & 7) * q8 + ((int)blockIdx.x >> 3);
    const int bx  = swz % nbx;
    const int by  = swz / nbx;

    const int tid  = threadIdx.x;
    const int lane = tid & 63;
    const int wid  = tid >> 6;
    const int wr   = wid / WC, wc = wid % WC;
    const int lr   = lane & 15, hi = lane >> 4;
    const size_t brow = (size_t)by * BM;
    const size_t bcol = (size_t)bx * BN;

    const f32x4 fzero = {0.f, 0.f, 0.f, 0.f};
    f32x4 acc[4][4];
#pragma unroll
    for (int m = 0; m < 4; ++m)
#pragma unroll
        for (int n = 0; n < 4; ++n) acc[m][n] = fzero;

    const int r8 = tid >> 3;      // staging row-within-round (0..63)
    const int c8 = tid & 7;       // staging 16B-chunk

#define STAGE(buf, kt) do {                                                     \
    _Pragma("unroll")                                                           \
    for (int i_ = 0; i_ < WR; ++i_) {                                           \
        const int row_ = i_ * 64 + r8;                                          \
        const int cg_  = c8 ^ (row_ & 7);                                       \
        gload_lds16(A + (brow + row_) * (size_t)K + (size_t)(kt) * 64 + cg_*8,  \
                    &As[buf][i_ * 4096 + tid * 8]);                             \
    }                                                                           \
    _Pragma("unroll")                                                           \
    for (int i_ = 0; i_ < WC; ++i_) {                                           \
        const int row_ = i_ * 64 + r8;                                          \
        const int cg_  = c8 ^ (row_ & 7);                                       \
        gload_lds16(Bm + (bcol + row_) * (size_t)K + (size_t)(kt) * 64 + cg_*8, \
                    &Bs[buf][i_ * 4096 + tid * 8]);                             \
    }                                                                           \
} while (0)

    const int NT = K >> 6;
    STAGE(0, 0);                  // WN loads in flight
    int cur = 0;

    for (int kt = 0; kt < NT; ++kt) {
        if (kt + 1 < NT) {
            STAGE(cur ^ 1, kt + 1);                              // +WN in flight
            asm volatile("s_waitcnt vmcnt(%0)" :: "i"(WN) : "memory"); // buf[cur] landed
        } else {
            asm volatile("s_waitcnt vmcnt(0)" ::: "memory");
        }
        __builtin_amdgcn_s_barrier();    // all waves' buf[cur] staged

#pragma unroll
        for (int kk = 0; kk < 2; ++kk) {
            bf16x8 af[4], bfr[4];
#pragma unroll
            for (int m = 0; m < 4; ++m) {
                const int row = wr * 64 + m * 16 + lr;
                af[m] = *reinterpret_cast<const bf16x8*>(
                    (const char*)&As[cur][0] + row * 128 +
                    ((kk * 64 + hi * 16) ^ ((row & 7) << 4)));
            }
#pragma unroll
            for (int n = 0; n < 4; ++n) {
                const int row = wc * 64 + n * 16 + lr;
                bfr[n] = *reinterpret_cast<const bf16x8*>(
                    (const char*)&Bs[cur][0] + row * 128 +
                    ((kk * 64 + hi * 16) ^ ((row & 7) << 4)));
            }
            __builtin_amdgcn_s_setprio(1);
#pragma unroll
            for (int m = 0; m < 4; ++m)
#pragma unroll
                for (int n = 0; n < 4; ++n)
                    acc[m][n] = __builtin_amdgcn_mfma_f32_16x16x32_bf16(
                        af[m], bfr[n], acc[m][n], 0, 0, 0);
            __builtin_amdgcn_s_setprio(0);
        }

        asm volatile("s_waitcnt lgkmcnt(0)" ::: "memory");  // my reads of buf[cur] done
        __builtin_amdgcn_s_barrier();                       // everyone's reads done
        cur ^= 1;
    }

#pragma unroll
    for (int m = 0; m < 4; ++m)
#pragma unroll
        for (int n = 0; n < 4; ++n)
#pragma unroll
            for (int r = 0; r < 4; ++r) {
                const size_t row = brow + wr * 64 + m * 16 + hi * 4 + r;
                const size_t col = bcol + wc * 64 + n * 16 + lr;
                const float bb = bias[col];
                const float v = acc[m][n][r] + (((int)col < scale_cols) ? bb * QSCALE : bb);
                if (BF16OUT)
                    ((bf16*)out)[row * (size_t)N + col] = (bf16)v;
                else
                    ((float*)out)[row * (size_t)N + col] = v;
            }
#undef STAGE
}

// ---------------- causal flash attention ----------------
// 64 q-rows/block (16/wave), KV tiles of 64, single-buffered, 24KB LDS ->
// high occupancy. Defer-max skips rescale on non-max-growing tiles.
__global__ __launch_bounds__(256) void attn_kernel(const bf16* __restrict__ qkv,
                                                   bf16* __restrict__ o) {
    const int bid = blockIdx.x;
    const int qt  = 31 - (bid >> 6);     // 32 q-tiles; longest first
    const int bh  = bid & 63;
    const int h   = bh & 15;
    const int b   = bh >> 4;
    const int qbase = qt * 64;

    const int tid  = threadIdx.x;
    const int wv   = tid >> 6;
    const int lane = tid & 63;
    const int lr   = lane & 15, hi = lane >> 4;

    __shared__ bf16 Ks[64 * 64];          // K tile [k][d], XOR-swizzled rows
    __shared__ bf16 Vt[64 * 64];          // V^T tile [d][k], XOR-swizzled rows
    __shared__ bf16 Pl[4 * 16 * 64];      // per-wave P [q][k], XOR-swizzled rows

    char* Ksb = (char*)Ks;
    char* Vtb = (char*)Vt;
    char* Pb  = (char*)(Pl + wv * 1024);

    const size_t tokbase = (size_t)b * SEQ;

    // Hoist Q (B-operand of swapped QK^T); Q already carries 0.125*log2e
    const bf16* qg = qkv + (tokbase + qbase + wv * 16 + lr) * (size_t)QKVF + h * 64;
    bf16x8 aq[2];
#pragma unroll
    for (int kk = 0; kk < 2; ++kk)
        aq[kk] = *reinterpret_cast<const bf16x8*>(qg + kk * 32 + hi * 8);

    const f32x4 fzero = {0.f, 0.f, 0.f, 0.f};
    f32x4 oacc[4];
#pragma unroll
    for (int n = 0; n < 4; ++n) oacc[n] = fzero;
    float m_r = -__builtin_inff();
    float l_r = 0.f;

    const int nkv = qt + 1;               // KV tiles of 64 covering [0, qbase+64)

    const int kp = tid >> 3;              // V staging: k-pair index
    const int vc = tid & 7;               // V staging: 16B d-chunk

    for (int kt = 0; kt < nkv; ++kt) {
        const size_t kvrow = tokbase + (size_t)kt * 64;
        __syncthreads();

        // --- stage K [64][64] via global_load_lds, pre-swizzled source
#pragma unroll
        for (int j = 0; j < 2; ++j) {
            const int kr = wv * 16 + j * 8 + (lane >> 3);
            const int cg = (lane & 7) ^ ((lane >> 3) & 7);
            gload_lds16(qkv + (kvrow + kr) * (size_t)QKVF + EMB + h * 64 + cg * 8,
                        &Ks[(wv * 16 + j * 8) * 64 + lane * 8]);
        }

        // --- stage V transposed: adjacent k-pair -> packed b32 writes
        {
            const bf16* vg = qkv + (kvrow + 2 * kp) * (size_t)QKVF + 2 * EMB + h * 64 + vc * 8;
            u16x8 v0 = *reinterpret_cast<const u16x8*>(vg);
            u16x8 v1 = *reinterpret_cast<const u16x8*>(vg + QKVF);
#pragma unroll
            for (int jj = 0; jj < 8; ++jj) {
                const int d = vc * 8 + jj;
                const unsigned int pr = (unsigned int)v0[jj] | ((unsigned int)v1[jj] << 16);
                *(unsigned int*)(Vtb + d * 128 + ((4 * kp) ^ (vc << 4))) = pr;
            }
        }
        __syncthreads();

        // --- S^T = K Q^T : lane holds S[q = lr][k = ktile*16 + hi*4 + r]
        f32x4 s[4];
#pragma unroll
        for (int ktile = 0; ktile < 4; ++ktile) s[ktile] = fzero;
#pragma unroll
        for (int ktile = 0; ktile < 4; ++ktile)
#pragma unroll
            for (int kk = 0; kk < 2; ++kk) {
                const int kr = ktile * 16 + lr;
                bf16x8 ak = *reinterpret_cast<const bf16x8*>(
                    Ksb + kr * 128 + ((kk * 64 + hi * 16) ^ ((kr & 7) << 4)));
                s[ktile] = __builtin_amdgcn_mfma_f32_16x16x32_bf16(
                    ak, aq[kk], s[ktile], 0, 0, 0);
            }

        // --- causal mask: only needed on diagonal tiles (wave-uniform test)
        if (kt * 64 + 63 > qbase + wv * 16) {
            const int qglob = qbase + wv * 16 + lr;
#pragma unroll
            for (int ktile = 0; ktile < 4; ++ktile) {
                const int kg0 = kt * 64 + ktile * 16 + hi * 4;
#pragma unroll
                for (int r = 0; r < 4; ++r)
                    if (kg0 + r > qglob) s[ktile][r] = -__builtin_inff();
            }
        }

        // --- online softmax (scores pre-scaled into exp2 domain)
        {
            float t4[4];
#pragma unroll
            for (int ktile = 0; ktile < 4; ++ktile)
                t4[ktile] = fmaxf(fmaxf(s[ktile][0], s[ktile][1]),
                                  fmaxf(s[ktile][2], s[ktile][3]));
            float tm = fmaxf(fmaxf(t4[0], t4[1]), fmaxf(t4[2], t4[3]));
            tm = fmaxf(tm, __shfl_xor(tm, 16));
            tm = fmaxf(tm, __shfl_xor(tm, 32));

            const bool defer = __all(tm <= m_r);
            const float mn = defer ? m_r : fmaxf(m_r, tm);

            float s4[4];
#pragma unroll
            for (int ktile = 0; ktile < 4; ++ktile) {
                float p0 = __builtin_amdgcn_exp2f(s[ktile][0] - mn);
                float p1 = __builtin_amdgcn_exp2f(s[ktile][1] - mn);
                float p2 = __builtin_amdgcn_exp2f(s[ktile][2] - mn);
                float p3 = __builtin_amdgcn_exp2f(s[ktile][3] - mn);
                s[ktile][0] = p0; s[ktile][1] = p1;
                s[ktile][2] = p2; s[ktile][3] = p3;
                s4[ktile] = (p0 + p1) + (p2 + p3);
            }
            float ts = (s4[0] + s4[1]) + (s4[2] + s4[3]);
            ts += __shfl_xor(ts, 16);
            ts += __shfl_xor(ts, 32);

            if (defer) {
                l_r += ts;
            } else {
                const float sc = __builtin_amdgcn_exp2f(m_r - mn);
                m_r = mn;
                l_r = l_r * sc + ts;
                float scb[4];
#pragma unroll
                for (int r = 0; r < 4; ++r) scb[r] = __shfl(sc, hi * 4 + r);
#pragma unroll
                for (int n = 0; n < 4; ++n)
#pragma unroll
                    for (int r = 0; r < 4; ++r) oacc[n][r] *= scb[r];
            }

            // write P (bf16) to wave-private LDS, swizzled rows
            const int q = lr;
#pragma unroll
            for (int ktile = 0; ktile < 4; ++ktile) {
                bf16x4 p4;
#pragma unroll
                for (int r = 0; r < 4; ++r) p4[r] = (bf16)s[ktile][r];
                *(bf16x4*)(Pb + q * 128 + ((ktile * 32 + hi * 8) ^ ((q & 7) << 4))) = p4;
            }
        }

        // --- PV: O += P V
#pragma unroll
        for (int kk = 0; kk < 2; ++kk) {
            const int q = lr;
            bf16x8 ap = *reinterpret_cast<const bf16x8*>(
                Pb + q * 128 + ((kk * 64 + hi * 16) ^ ((q & 7) << 4)));
#pragma unroll
            for (int n = 0; n < 4; ++n) {
                const int d = n * 16 + lr;
                bf16x8 bv = *reinterpret_cast<const bf16x8*>(
                    Vtb + d * 128 + ((kk * 64 + hi * 16) ^ (((d >> 3) & 7) << 4)));
                oacc[n] = __builtin_amdgcn_mfma_f32_16x16x32_bf16(
                    ap, bv, oacc[n], 0, 0, 0);
            }
        }
    }

    // --- epilogue: normalize and store
    {
        const float linv = 1.f / l_r;
        float li[4];
#pragma unroll
        for (int r = 0; r < 4; ++r) li[r] = __shfl(linv, hi * 4 + r);
        bf16* og = o + (tokbase + qbase + wv * 16) * (size_t)EMB + h * 64;
#pragma unroll
        for (int n = 0; n < 4; ++n)
#pragma unroll
            for (int r = 0; r < 4; ++r)
                og[(hi * 4 + r) * (size_t)EMB + n * 16 + lr] =
                    (bf16)(oacc[n][r] * li[r]);
    }
}

// ---------------- launcher ----------------
extern "C" void kernel_launch(void* const* d_in, const int* in_sizes, int n_in,
                              void* d_out, int out_size, void* d_ws, size_t ws_size,
                              hipStream_t stream) {
    const float* x     = (const float*)d_in[0];
    const float* qkv_w = (const float*)d_in[1];
    const float* qkv_b = (const float*)d_in[2];
    const float* out_w = (const float*)d_in[3];
    const float* out_b = (const float*)d_in[4];
    float* out = (float*)d_out;

    char* ws = (char*)d_ws;
    bf16* x_bf    = (bf16*)(ws);                                  // 16 MB
    bf16* qkvw_bf = (bf16*)(ws + 16777216);                       //  6 MB
    bf16* outw_bf = (bf16*)(ws + 23068672);                       //  2 MB
    bf16* qkv_bf  = (bf16*)(ws + 25165824);                       // 48 MB
    bf16* o_bf    = (bf16*)(ws + 75497472);                       // 16 MB

    cvt_f32_bf16<<<8192, 256, 0, stream>>>(x,     x_bf,    NTOK * EMB);
    cvt_qkvw_bf16<<<3072, 256, 0, stream>>>(qkv_w, qkvw_bf);
    cvt_f32_bf16<<<1024, 256, 0, stream>>>(out_w, outw_bf, EMB * EMB);

    // QKV projection: BM=128, BN=256 -> grid 64*12 = 768 (exact 3 rounds/CU)
    gemm_bt8<2, 4, true><<<(NTOK / 128) * (QKVF / 256), 512, 0, stream>>>(
        x_bf, qkvw_bf, qkv_b, qkv_bf, NTOK, QKVF, EMB, EMB);

    // causal attention -> bf16 [8192,1024]; 64-row q-tiles, grid 2048
    attn_kernel<<<4 * 16 * (SEQ / 64), 256, 0, stream>>>(qkv_bf, o_bf);

    // output projection: BM=256, BN=128 -> grid 32*8 = 256 (exact 1/CU)
    gemm_bt8<4, 2, false><<<(NTOK / 256) * (EMB / 128), 512, 0, stream>>>(
        o_bf, outw_bf, out_b, out, NTOK, EMB, EMB, 0);
}